// Round 1
// baseline (7721.734 us; speedup 1.0000x reference)
//
#include <hip/hip_runtime.h>
#include <stdint.h>
#include <math.h>

// Problem constants (from reference)
#define NF 1568     // IN_FEATURES
#define PPOP 784    // pixels per population (2 populations)
#define NOUT 10
#define NB 64       // batch
#define NT 256      // num steps
#define RINGN 20    // TWO_SIGMA

__device__ __forceinline__ uint32_t rotl32(uint32_t v, int r){ return (v<<r)|(v>>(32-r)); }

// JAX threefry2x32 (20 rounds), bit-exact.
__device__ __forceinline__ void tf2x32(uint32_t k0, uint32_t k1, uint32_t x0, uint32_t x1,
                                       uint32_t& o0, uint32_t& o1){
  uint32_t ks2 = k0 ^ k1 ^ 0x1BD11BDAu;
  x0 += k0; x1 += k1;
#define TF_RND(r) { x0 += x1; x1 = rotl32(x1,(r)); x1 ^= x0; }
  TF_RND(13) TF_RND(15) TF_RND(26) TF_RND(6)
  x0 += k1;  x1 += ks2 + 1u;
  TF_RND(17) TF_RND(29) TF_RND(16) TF_RND(24)
  x0 += ks2; x1 += k0 + 2u;
  TF_RND(13) TF_RND(15) TF_RND(26) TF_RND(6)
  x0 += k0;  x1 += k1 + 3u;
  TF_RND(17) TF_RND(29) TF_RND(16) TF_RND(24)
  x0 += k1;  x1 += ks2 + 4u;
  TF_RND(13) TF_RND(15) TF_RND(26) TF_RND(6)
  x0 += ks2; x1 += k0 + 5u;
#undef TF_RND
  o0 = x0; o1 = x1;
}

// ---------- init: key chain, prior normalize, zero ring state ----------
__global__ void kInit(const float* __restrict__ prior_in, double* __restrict__ prior,
                      uint32_t* __restrict__ sk, int* __restrict__ ring,
                      int* __restrict__ ring_sum, int* __restrict__ cum){
  int tid = threadIdx.x;
  for (int k = tid; k < RINGN*NB*NOUT; k += 256) ring[k] = 0;
  for (int k = tid; k < NB*NOUT; k += 256){ ring_sum[k] = 0; cum[k] = 0; }
  if (tid == 0){
    // key chain: key0=(0,42); per step sk_t = tf(key,(0,1)), key = tf(key,(0,0))
    uint32_t k0 = 0u, k1 = 42u;
    for (int t = 0; t < NT; t++){
      uint32_t a,b; tf2x32(k0,k1,0u,1u,a,b); sk[2*t] = a; sk[2*t+1] = b;
      uint32_t c,d; tf2x32(k0,k1,0u,0u,c,d); k0 = c; k1 = d;
    }
  }
  if (tid == 1){
    double v[NOUT];
    double m = -1e300;
    for (int o = 0; o < NOUT; o++){
      double p = (double)prior_in[o];
      p = fmin(0.0, fmax(-7.0, p));
      v[o] = p; m = fmax(m, p);
    }
    double s = 0.0;
    for (int o = 0; o < NOUT; o++) s += exp(v[o]-m);
    double lse = log(s) + m;
    for (int o = 0; o < NOUT; o++) prior[o] = v[o] - lse;
  }
}

// ---------- init LL: clip + per-population-pair logsumexp, store transposed [o][i] ----------
__global__ void kInitLL(const float* __restrict__ LL_in, double* __restrict__ LLT){
  int u = blockIdx.x*256 + threadIdx.x;   // (p,o) flat
  int p = u/NOUT, o = u%NOUT;
  if (p >= PPOP) return;
  double l0 = fmin(0.0, fmax(-7.0, (double)LL_in[p*NOUT+o]));
  double l1 = fmin(0.0, fmax(-7.0, (double)LL_in[(p+PPOP)*NOUT+o]));
  double m = fmax(l0,l1);
  double lse = log(exp(l0-m)+exp(l1-m)) + m;
  LLT[o*NF + p]        = l0 - lse;
  LLT[o*NF + p + PPOP] = l1 - lse;
}

// ---------- spike-trace precompute, packed uint16 per (t,b,i) ----------
// bits 0-3: tp_sigma (<=10); bits 4-11: tp_s2inf (<=246); bit12: potential; bit13: no_pre; bit14: x
__global__ void kTrace(const int* __restrict__ x, uint16_t* __restrict__ trace){
  int b = blockIdx.y;
  int i = blockIdx.x*256 + threadIdx.x;
  if (i >= NF) return;
  const int* xb = x + (size_t)b*NT*NF + i;
  uint64_t hist = 0; int total = 0;
  for (int t = 0; t < NT; t++){
    int xv = xb[(size_t)t*NF];
    hist = (hist << 1) | (uint64_t)(uint32_t)xv;
    total += xv;
    int tps  = __popcll(hist & 0x3FFull);               // spikes in [t-9, t]
    int tps2 = total - tps;                             // spikes <= t-10
    int pot  = (tps > 0) ? 1 : 0;
    int npre = ((hist & 0x000000FFFFFFFFFEull) == 0) ? 1 : 0;  // no spikes in [t-39, t-1]
    trace[((size_t)t*NB + b)*NF + i] =
        (uint16_t)(tps | (tps2 << 4) | (pot << 12) | (npre << 13) | (xv << 14));
  }
}

// ---------- gumbel table: gum[t][b*10+o], JAX partitionable 64-bit path ----------
__global__ void kGum(const uint32_t* __restrict__ sk, double* __restrict__ gum){
  int t = blockIdx.x;
  uint32_t k0 = sk[2*t], k1 = sk[2*t+1];
  for (int idx = threadIdx.x; idx < NB*NOUT; idx += blockDim.x){
    uint32_t h,l; tf2x32(k0,k1,0u,(uint32_t)idx,h,l);
    uint64_t bits = ((uint64_t)h << 32) | (uint64_t)l;
    uint64_t fb = (bits >> 12) | 0x3FF0000000000000ull;
    double u01 = __longlong_as_double((long long)fb) - 1.0;
    double u = fmax(2.2250738585072014e-308, u01);     // minval = DBL tiny
    gum[(size_t)t*NB*NOUT + idx] = -log(-log(u));
  }
}

// ---------- Phase A: logits + categorical sample + ring/tpost bookkeeping ----------
__global__ void kA(const uint16_t* __restrict__ trace, const double* __restrict__ LLT,
                   const double* __restrict__ prior, const double* __restrict__ gum,
                   int* __restrict__ winner_g, int* __restrict__ tpost_g, int* __restrict__ tpinf_g,
                   int* __restrict__ ring, int* __restrict__ ring_sum, int* __restrict__ cum,
                   int t){
  int b = blockIdx.x, tid = threadIdx.x;
  __shared__ double red[NOUT*256];
  __shared__ int wsh;
  double acc[NOUT];
#pragma unroll
  for (int o = 0; o < NOUT; o++) acc[o] = 0.0;
  const uint16_t* tr = trace + ((size_t)t*NB + b)*NF;
  for (int i = tid; i < NF; i += 256){
    if (tr[i] & (1u<<12)){
#pragma unroll
      for (int o = 0; o < NOUT; o++) acc[o] += LLT[o*NF + i];
    }
  }
#pragma unroll
  for (int o = 0; o < NOUT; o++) red[o*256 + tid] = acc[o];
  __syncthreads();
  for (int s = 128; s > 0; s >>= 1){
    if (tid < s){
#pragma unroll
      for (int o = 0; o < NOUT; o++) red[o*256 + tid] += red[o*256 + tid + s];
    }
    __syncthreads();
  }
  if (tid == 0){
    const double* g = gum + ((size_t)t*NB + b)*NOUT;
    double best = -1e308; int w = 0;
    for (int o = 0; o < NOUT; o++){
      double v = red[o*256] + prior[o] + g[o];
      if (v > best){ best = v; w = o; }        // first-max, matches jnp.argmax
    }
    wsh = w; winner_g[b] = w;
  }
  __syncthreads();
  if (tid < NOUT){
    int o = tid, idx = b*NOUT + o;
    int rs = ring_sum[idx];
    tpost_g[idx] = rs;                 // winners in [t-20, t-1]
    tpinf_g[idx] = cum[idx] - rs;      // winners older than 2*sigma
    int slot = t % RINGN;
    int* rp = &ring[(slot*NB + b)*NOUT + o];
    int wi = (wsh == o) ? 1 : 0;
    ring_sum[idx] = rs + wi - *rp;
    *rp = wi;
    cum[idx] += wi;
  }
}

// ---------- Phase B: LL update + pair logsumexp; block 31: prior update ----------
__global__ void kB(const uint16_t* __restrict__ trace, double* __restrict__ LLT,
                   double* __restrict__ prior,
                   const int* __restrict__ winner_g, const int* __restrict__ tpost_g,
                   const int* __restrict__ tpinf_g, int t){
  int tid = threadIdx.x, blk = blockIdx.x;
  double scale = 1e-3 / (double)(t + 1);
  if (blk == 31){
    __shared__ double v_s[NOUT];
    __shared__ double lse_s;
    if (tid < NOUT){
      int c = 0;
      for (int b = 0; b < NB; b++) c += (winner_g[b] == tid) ? 1 : 0;
      double ps = (double)c;
      double p0 = prior[tid];
      p0 = p0 + ((exp(-p0) - 1.0)*ps - (1.0 - ps))*scale;
      p0 = fmin(0.0, fmax(-7.0, p0));
      v_s[tid] = p0;
    }
    __syncthreads();
    if (tid == 0){
      double m = v_s[0];
      for (int o = 1; o < NOUT; o++) m = fmax(m, v_s[o]);
      double s = 0.0;
      for (int o = 0; o < NOUT; o++) s += exp(v_s[o]-m);
      lse_s = log(s) + m;
    }
    __syncthreads();
    if (tid < NOUT) prior[tid] = v_s[tid] - lse_s;
    return;
  }
  __shared__ int win_s[NB];
  __shared__ int tp_s[NB*NOUT];
  __shared__ int ti_s[NB*NOUT];
  if (tid < NB) win_s[tid] = winner_g[tid];
  for (int k = tid; k < NB*NOUT; k += 256){ tp_s[k] = tpost_g[k]; ti_s[k] = tpinf_g[k]; }
  __syncthreads();
  int u = blk*256 + tid;
  int p = u/NOUT, o = u%NOUT;
  if (p >= PPOP) return;
  const uint16_t* trb = trace + (size_t)t*NB*NF;
  int ltp0=0, ltd0=0, pp0=0, po0=0;
  int ltp1=0, ltd1=0, pp1=0, po1=0;
  for (int b = 0; b < NB; b++){
    uint16_t t0 = trb[(size_t)b*NF + p];
    uint16_t t1 = trb[(size_t)b*NF + p + PPOP];
    int tp = tp_s[b*NOUT + o], ti = ti_s[b*NOUT + o];
    if (win_s[b] == o){
      ltp0 += t0 & 15;  ltd0 += (t0 >> 4) & 255;
      ltp1 += t1 & 15;  ltd1 += (t1 >> 4) & 255;
    }
    if (t0 & (1u<<14)) pp0 += tp;
    if (t0 & (1u<<13)) po0 += ti;
    if (t1 & (1u<<14)) pp1 += tp;
    if (t1 & (1u<<13)) po1 += ti;
  }
  double l0 = LLT[o*NF + p], l1 = LLT[o*NF + p + PPOP];
  l0 = l0 + ((exp(-l0) - 1.0)*(double)ltp0 - (double)ltd0 - (double)pp0 - (double)po0)*scale;
  l1 = l1 + ((exp(-l1) - 1.0)*(double)ltp1 - (double)ltd1 - (double)pp1 - (double)po1)*scale;
  l0 = fmin(0.0, fmax(-7.0, l0));
  l1 = fmin(0.0, fmax(-7.0, l1));
  double m = fmax(l0,l1);
  double lse = log(exp(l0-m)+exp(l1-m)) + m;
  LLT[o*NF + p]        = l0 - lse;
  LLT[o*NF + p + PPOP] = l1 - lse;
}

// ---------- output: argmax over accumulated winner counts ----------
__global__ void kOut(const int* __restrict__ cum, int* __restrict__ out){
  int b = threadIdx.x;
  if (b >= NB) return;
  int best = cum[b*NOUT]; int w = 0;
  for (int o = 1; o < NOUT; o++){
    int v = cum[b*NOUT + o];
    if (v > best){ best = v; w = o; }
  }
  out[b] = w;
}

static inline size_t alignup(size_t v){ return (v + 255) & ~(size_t)255; }

extern "C" void kernel_launch(void* const* d_in, const int* in_sizes, int n_in,
                              void* d_out, int out_size, void* d_ws, size_t ws_size,
                              hipStream_t stream){
  (void)in_sizes; (void)n_in; (void)out_size; (void)ws_size;
  const int*   x        = (const int*)d_in[0];
  const float* LL_in    = (const float*)d_in[1];   // f64 in reference; harness canonical f32
  const float* prior_in = (const float*)d_in[2];
  int* out = (int*)d_out;                          // argmax indices (int64 ref -> int32 buffer)

  char* ws = (char*)d_ws;
  size_t off = 0;
  double*   LLT      = (double*)(ws + off); off += alignup(NOUT*NF*sizeof(double));
  double*   prior    = (double*)(ws + off); off += alignup(NOUT*sizeof(double));
  uint32_t* sk       = (uint32_t*)(ws + off); off += alignup(NT*2*sizeof(uint32_t));
  double*   gum      = (double*)(ws + off); off += alignup((size_t)NT*NB*NOUT*sizeof(double));
  int*      ring     = (int*)(ws + off); off += alignup((size_t)RINGN*NB*NOUT*sizeof(int));
  int*      ring_sum = (int*)(ws + off); off += alignup(NB*NOUT*sizeof(int));
  int*      cum      = (int*)(ws + off); off += alignup(NB*NOUT*sizeof(int));
  int*      winner   = (int*)(ws + off); off += alignup(NB*sizeof(int));
  int*      tpost    = (int*)(ws + off); off += alignup(NB*NOUT*sizeof(int));
  int*      tpinf    = (int*)(ws + off); off += alignup(NB*NOUT*sizeof(int));
  uint16_t* trace    = (uint16_t*)(ws + off); off += alignup((size_t)NT*NB*NF*sizeof(uint16_t));
  // total ~52.9 MB of d_ws

  kInit<<<1, 256, 0, stream>>>(prior_in, prior, sk, ring, ring_sum, cum);
  kInitLL<<<31, 256, 0, stream>>>(LL_in, LLT);
  kTrace<<<dim3((NF+255)/256, NB), 256, 0, stream>>>(x, trace);
  kGum<<<NT, 256, 0, stream>>>(sk, gum);

  for (int t = 0; t < NT; t++){
    kA<<<NB, 256, 0, stream>>>(trace, LLT, prior, gum, winner, tpost, tpinf,
                               ring, ring_sum, cum, t);
    kB<<<32, 256, 0, stream>>>(trace, LLT, prior, winner, tpost, tpinf, t);
  }
  kOut<<<1, 64, 0, stream>>>(cum, out);
}